// Round 1
// baseline (122.803 us; speedup 1.0000x reference)
//
#include <hip/hip_runtime.h>

#define B_N   256
#define IN_N  1024
#define OUT_N 512
#define P_N   1000
#define NS_N  128

__device__ __forceinline__ float sigmoid_f(float z) { return 1.0f / (1.0f + __expf(-z)); }

// ---------------- feedback: fb[b] = sigmoid(x[b,:]·fb_w + fb_b) ----------------
__global__ __launch_bounds__(256) void fb_kernel(const float* __restrict__ x,
                                                 const float* __restrict__ fb_w,
                                                 const float* __restrict__ fb_b,
                                                 float* __restrict__ fb_out) {
    int b = blockIdx.x;
    int t = threadIdx.x;
    const float4* xr = reinterpret_cast<const float4*>(x + (size_t)b * IN_N);
    const float4* wr = reinterpret_cast<const float4*>(fb_w);
    float4 xv = xr[t];
    float4 wv = wr[t];
    float s = xv.x * wv.x + xv.y * wv.y + xv.z * wv.z + xv.w * wv.w;
    __shared__ float red[256];
    red[t] = s;
    __syncthreads();
    for (int off = 128; off >= 1; off >>= 1) {
        if (t < off) red[t] += red[t + off];
        __syncthreads();
    }
    if (t == 0) fb_out[b] = sigmoid_f(red[0] + fb_b[0]);
}

// ------------- SDE time reduction: T[b, i*3+k] coefficients ------------------
// paths[t] = fb*sd * sum_{s<=t} retain^{t-s} eps[s]
// S   = sum_t paths[t] = fb*sd*A,  A = (sumE - retain*L) / (1-retain)
// last= fb*sd*L, L = sum_s retain^{127-s} eps[s];  first = fb*sd*eps[0]
// mean-conv coefficients: k=0 -> (S-last), k=1 -> S, k=2 -> (S-first), all /NS
__global__ __launch_bounds__(256) void sde_reduce_kernel(const float* __restrict__ noise,
                                                         const float* __restrict__ fb,
                                                         const float* __restrict__ decay_param,
                                                         float* __restrict__ Tcat) {
    int blk = blockIdx.x;
    int b = blk >> 2;
    int i = ((blk & 3) << 8) + threadIdx.x;
    if (i >= P_N) return;

    float dp = decay_param[0];
    float decay = sigmoid_f(dp) * 0.5f;
    const float dt = 1.0f / NS_N;
    float retain = 1.0f - decay * dt;
    float inv_omr = 1.0f / (decay * dt);

    const float* np_ = noise + (size_t)b * NS_N * P_N + i;
    float sumE = 0.f, L = 0.f, F = 0.f;
    float rp = 1.0f;  // retain^{127-s}, s descending from 127
    #pragma unroll 8
    for (int s = NS_N - 1; s >= 0; --s) {
        float e = np_[(size_t)s * P_N];
        sumE += e;
        L += rp * e;
        if (s == 0) F = e;
        rp *= retain;
    }
    float A = (sumE - retain * L) * inv_omr;
    float sd = sqrtf(dt);
    float scale = fb[b] * sd * (1.0f / NS_N);

    float* t = Tcat + (size_t)b * (3 * P_N) + 3 * i;
    t[0] = scale * (A - L);
    t[1] = scale * A;
    t[2] = scale * (A - F);
}

// ---------------- generic f32 NT GEMM, split-K into partials -----------------
// Cpart[z][M][N] = A[M, kslice] * B[N, kslice]^T   (row-major A,B)
template <int BM, int BN, int BK>
__global__ __launch_bounds__(256) void gemm_nt_splitk(const float* __restrict__ A,
                                                      const float* __restrict__ Bm,
                                                      float* __restrict__ Cpart,
                                                      int M, int N, int K, int Kper) {
    __shared__ float As[BK][BM + 4];
    __shared__ float Bs[BK][BN + 4];

    int n0 = blockIdx.x * BN;
    int m0 = blockIdx.y * BM;
    int z  = blockIdx.z;
    int k_begin = z * Kper;                  // Kper is a multiple of BK (and 4)
    int k_end   = min(K, k_begin + Kper);

    int tid = threadIdx.x;
    int tn_ = tid & 15;   // 0..15 -> cols 4*tn_..+3
    int tm_ = tid >> 4;   // 0..15 -> rows 4*tm_..+3

    float acc[4][4] = {};

    int ar = tid >> 2;            // 0..63 (tile row)
    int ac = (tid & 3) << 2;      // 0,4,8,12 (k offset)

    for (int kt = k_begin; kt < k_end; kt += BK) {
        int gk = kt + ac;
        // stage A
        {
            int am = m0 + ar;
            float4 av = {0.f, 0.f, 0.f, 0.f};
            if (am < M) {
                const float* ap = A + (size_t)am * K + gk;
                if (gk + 3 < k_end) {
                    av = *reinterpret_cast<const float4*>(ap);
                } else {
                    if (gk + 0 < k_end) av.x = ap[0];
                    if (gk + 1 < k_end) av.y = ap[1];
                    if (gk + 2 < k_end) av.z = ap[2];
                    if (gk + 3 < k_end) av.w = ap[3];
                }
            }
            As[ac + 0][ar] = av.x;
            As[ac + 1][ar] = av.y;
            As[ac + 2][ar] = av.z;
            As[ac + 3][ar] = av.w;
        }
        // stage B
        {
            int bn = n0 + ar;
            float4 bv = {0.f, 0.f, 0.f, 0.f};
            if (bn < N) {
                const float* bp = Bm + (size_t)bn * K + gk;
                if (gk + 3 < k_end) {
                    bv = *reinterpret_cast<const float4*>(bp);
                } else {
                    if (gk + 0 < k_end) bv.x = bp[0];
                    if (gk + 1 < k_end) bv.y = bp[1];
                    if (gk + 2 < k_end) bv.z = bp[2];
                    if (gk + 3 < k_end) bv.w = bp[3];
                }
            }
            Bs[ac + 0][ar] = bv.x;
            Bs[ac + 1][ar] = bv.y;
            Bs[ac + 2][ar] = bv.z;
            Bs[ac + 3][ar] = bv.w;
        }
        __syncthreads();
        #pragma unroll
        for (int kk = 0; kk < BK; ++kk) {
            float4 a = *reinterpret_cast<const float4*>(&As[kk][tm_ << 2]);
            float4 b = *reinterpret_cast<const float4*>(&Bs[kk][tn_ << 2]);
            acc[0][0] += a.x * b.x; acc[0][1] += a.x * b.y; acc[0][2] += a.x * b.z; acc[0][3] += a.x * b.w;
            acc[1][0] += a.y * b.x; acc[1][1] += a.y * b.y; acc[1][2] += a.y * b.z; acc[1][3] += a.y * b.w;
            acc[2][0] += a.z * b.x; acc[2][1] += a.z * b.y; acc[2][2] += a.z * b.z; acc[2][3] += a.z * b.w;
            acc[3][0] += a.w * b.x; acc[3][1] += a.w * b.y; acc[3][2] += a.w * b.z; acc[3][3] += a.w * b.w;
        }
        __syncthreads();
    }

    float* cp = Cpart + (size_t)z * M * N;
    #pragma unroll
    for (int i = 0; i < 4; ++i) {
        int m = m0 + (tm_ << 2) + i;
        if (m >= M) continue;
        #pragma unroll
        for (int j = 0; j < 4; ++j) {
            int n = n0 + (tn_ << 2) + j;
            if (n < N) cp[(size_t)m * N + n] = acc[i][j];
        }
    }
}

// ----------------- sum split-K partials + bias -------------------------------
__global__ __launch_bounds__(256) void reduce_bias_kernel(const float* __restrict__ Cpart,
                                                          const float* __restrict__ bias,
                                                          float* __restrict__ Cout,
                                                          int M, int N, int KS) {
    int idx = blockIdx.x * 256 + threadIdx.x;
    if (idx >= M * N) return;
    int n = idx % N;
    float s = bias[n];
    for (int z = 0; z < KS; ++z) s += Cpart[(size_t)z * M * N + idx];
    Cout[idx] = s;
}

extern "C" void kernel_launch(void* const* d_in, const int* in_sizes, int n_in,
                              void* d_out, int out_size, void* d_ws, size_t ws_size,
                              hipStream_t stream) {
    const float* x           = (const float*)d_in[0];
    const float* noise       = (const float*)d_in[1];
    const float* fb_w        = (const float*)d_in[2];
    const float* fb_b        = (const float*)d_in[3];
    const float* decay_param = (const float*)d_in[4];
    const float* conv_w      = (const float*)d_in[5];  // [P, P, 3] == [P][3P] flat NT layout
    const float* conv_b      = (const float*)d_in[6];
    const float* out_w       = (const float*)d_in[7];  // [OUT, P]
    const float* out_b       = (const float*)d_in[8];
    float* out = (float*)d_out;

    // workspace layout (floats)
    float* ws = (float*)d_ws;
    float* fb    = ws;                       // 256
    float* Tcat  = fb + 256;                 // 256*3000
    float* part1 = Tcat + (size_t)B_N * 3 * P_N;        // 4*256*1000
    float* agg   = part1 + (size_t)4 * B_N * P_N;       // 256*1000
    float* part2 = agg + (size_t)B_N * P_N;             // 4*256*512

    // 1. feedback GEMV
    fb_kernel<<<B_N, 256, 0, stream>>>(x, fb_w, fb_b, fb);

    // 2. SDE time reduction -> Tcat [256, 3000]
    sde_reduce_kernel<<<B_N * 4, 256, 0, stream>>>(noise, fb, decay_param, Tcat);

    // 3. GEMM1: agg_part = Tcat[256,3000] * conv_w[1000,3000]^T  (split-K=4)
    {
        int M = B_N, N = P_N, K = 3 * P_N, KS = 4;
        int Kper = ((K + KS - 1) / KS + 15) & ~15;  // 752, multiple of 16
        dim3 grid((N + 63) / 64, (M + 63) / 64, KS);
        gemm_nt_splitk<64, 64, 16><<<grid, 256, 0, stream>>>(Tcat, conv_w, part1, M, N, K, Kper);
        int total = M * N;
        reduce_bias_kernel<<<(total + 255) / 256, 256, 0, stream>>>(part1, conv_b, agg, M, N, KS);
    }

    // 4. GEMM2: out_part = agg[256,1000] * out_w[512,1000]^T  (split-K=4)
    {
        int M = B_N, N = OUT_N, K = P_N, KS = 4;
        int Kper = ((K + KS - 1) / KS + 15) & ~15;  // 256
        dim3 grid((N + 63) / 64, (M + 63) / 64, KS);
        gemm_nt_splitk<64, 64, 16><<<grid, 256, 0, stream>>>(agg, out_w, part2, M, N, K, Kper);
        int total = M * N;
        reduce_bias_kernel<<<(total + 255) / 256, 256, 0, stream>>>(part2, out_b, out, M, N, KS);
    }
}

// Round 2
// 71.201 us; speedup vs baseline: 1.7247x; 1.7247x over previous
//
#include <hip/hip_runtime.h>

#define B_N   256
#define IN_N  1024
#define OUT_N 512
#define P_N   1000
#define NS_N  128

// padded GEMM dims
#define K1P   3072   // pad of 3*P_N
#define N1P   1024   // pad of P_N
#define K2P   1024   // pad of P_N (GEMM2 K)
#define SK    16     // split-K factor (both GEMMs)

typedef __attribute__((ext_vector_type(8))) short short8v;
typedef __attribute__((ext_vector_type(4))) float f32x4;

__device__ __forceinline__ float sigmoid_f(float z) { return 1.0f / (1.0f + __expf(-z)); }

__device__ __forceinline__ unsigned short f2bf(float x) {
    union { float f; unsigned u; } v; v.f = x;
    unsigned r = v.u + 0x7fffu + ((v.u >> 16) & 1u);   // RNE
    return (unsigned short)(r >> 16);
}
__device__ __forceinline__ float bf2f(unsigned short h) {
    union { unsigned u; float f; } v; v.u = ((unsigned)h) << 16;
    return v.f;
}
__device__ __forceinline__ void split_hilo(float x, unsigned short& h, unsigned short& l) {
    h = f2bf(x);
    l = f2bf(x - bf2f(h));
}

// ---------------- feedback: fb[b] = sigmoid(x[b,:]·fb_w + fb_b) ----------------
__global__ __launch_bounds__(256) void fb_kernel(const float* __restrict__ x,
                                                 const float* __restrict__ fb_w,
                                                 const float* __restrict__ fb_b,
                                                 float* __restrict__ fb_out) {
    int b = blockIdx.x;
    int t = threadIdx.x;
    const float4* xr = reinterpret_cast<const float4*>(x + (size_t)b * IN_N);
    const float4* wr = reinterpret_cast<const float4*>(fb_w);
    float4 xv = xr[t];
    float4 wv = wr[t];
    float s = xv.x * wv.x + xv.y * wv.y + xv.z * wv.z + xv.w * wv.w;
    __shared__ float red[256];
    red[t] = s;
    __syncthreads();
    for (int off = 128; off >= 1; off >>= 1) {
        if (t < off) red[t] += red[t + off];
        __syncthreads();
    }
    if (t == 0) fb_out[b] = sigmoid_f(red[0] + fb_b[0]);
}

// ------------- SDE time reduction -> T coefficients, emitted as bf16 hi/lo ----
// paths[t] = fb*sd * sum_{s<=t} retain^{t-s} eps[s]
// L = sum_s retain^{127-s} eps[s]; A = (sumE - retain*L)/(1-retain); F = eps[0]
// T[b, i*3+k]: k=0 -> scale*(A-L), k=1 -> scale*A, k=2 -> scale*(A-F)
__global__ __launch_bounds__(256) void sde_reduce_kernel(const float* __restrict__ noise,
                                                         const float* __restrict__ fb,
                                                         const float* __restrict__ decay_param,
                                                         unsigned short* __restrict__ Thi,
                                                         unsigned short* __restrict__ Tlo) {
    int blk = blockIdx.x;
    int b = blk >> 2;
    int i = ((blk & 3) << 8) + threadIdx.x;   // 0..1023

    float t0 = 0.f, t1 = 0.f, t2 = 0.f;
    if (i < P_N) {
        float dp = decay_param[0];
        float decay = sigmoid_f(dp) * 0.5f;
        const float dt = 1.0f / NS_N;
        float retain = 1.0f - decay * dt;
        float inv_omr = 1.0f / (decay * dt);

        const float* np_ = noise + (size_t)b * NS_N * P_N + i;
        float sumE = 0.f, L = 0.f, F = 0.f;
        float rp = 1.0f;  // retain^{127-s}, s descending
        #pragma unroll 8
        for (int s = NS_N - 1; s >= 0; --s) {
            float e = np_[(size_t)s * P_N];
            sumE += e;
            L += rp * e;
            if (s == 0) F = e;
            rp *= retain;
        }
        float A = (sumE - retain * L) * inv_omr;
        float sd = sqrtf(dt);
        float scale = fb[b] * sd * (1.0f / NS_N);
        t0 = scale * (A - L);
        t1 = scale * A;
        t2 = scale * (A - F);
    }
    size_t base = (size_t)b * K1P + 3 * (size_t)i;   // i<1024 -> 3i+2 <= 3071
    unsigned short h, l;
    split_hilo(t0, h, l); Thi[base + 0] = h; Tlo[base + 0] = l;
    split_hilo(t1, h, l); Thi[base + 1] = h; Tlo[base + 1] = l;
    split_hilo(t2, h, l); Thi[base + 2] = h; Tlo[base + 2] = l;
}

// ------------- pad + f32 -> bf16 hi/lo conversion (generic 2D) ----------------
__global__ __launch_bounds__(256) void cvt_pad_kernel(const float* __restrict__ src,
                                                      unsigned short* __restrict__ hi,
                                                      unsigned short* __restrict__ lo,
                                                      int rows_src, int cols_src,
                                                      int cols_dst, int total) {
    int idx = blockIdx.x * 256 + threadIdx.x;
    if (idx >= total) return;
    int r = idx / cols_dst;
    int c = idx - r * cols_dst;
    float v = (r < rows_src && c < cols_src) ? src[(size_t)r * cols_src + c] : 0.f;
    unsigned short h, l;
    split_hilo(v, h, l);
    hi[idx] = h; lo[idx] = l;
}

// ------------- bf16 hi/lo MFMA NT GEMM, split-K -> f32 partials ---------------
// C = (Ahi+Alo)[M,K] * (Bhi+Blo)[N,K]^T, dropping lo*lo.  BM=BN=128, BK=64.
// 256 threads = 4 waves; wave computes a 64x64 sub-tile as 4x4 frags of 16x16.
// LDS tiles XOR-swizzled at 16B-granule level: slot(row,g) holds granule g^(row&7).
__global__ __launch_bounds__(256) void gemm_hilo_mfma(const unsigned short* __restrict__ Ahi,
                                                      const unsigned short* __restrict__ Alo,
                                                      const unsigned short* __restrict__ Bhi,
                                                      const unsigned short* __restrict__ Blo,
                                                      float* __restrict__ Cpart,
                                                      int ldk, int Kper, int ldc) {
    __shared__ __align__(16) unsigned short As_hi[128 * 64];
    __shared__ __align__(16) unsigned short As_lo[128 * 64];
    __shared__ __align__(16) unsigned short Bs_hi[128 * 64];
    __shared__ __align__(16) unsigned short Bs_lo[128 * 64];

    const int tid  = threadIdx.x;
    const int lane = tid & 63;
    const int wave = tid >> 6;
    const int r15  = lane & 15;
    const int g4   = lane >> 4;
    const int n0 = blockIdx.x * 128;
    const int m0 = blockIdx.y * 128;
    const size_t kbeg = (size_t)blockIdx.z * Kper;

    f32x4 acc[4][4] = {};

    const int wr = (wave >> 1) * 64;
    const int wc = (wave & 1) * 64;

    for (int kt = 0; kt < Kper; kt += 64) {
        const size_t kk0 = kbeg + kt;
        // stage A/B tiles (hi+lo): 4 chunks of 8 bf16 per thread per array
        #pragma unroll
        for (int c = 0; c < 4; ++c) {
            int chunk = tid + c * 256;        // 0..1023
            int row = chunk >> 3;             // 0..127
            int g   = chunk & 7;              // 16B granule in row
            int ldsoff = row * 64 + ((g ^ (row & 7)) << 3);
            const size_t ga = (size_t)(m0 + row) * ldk + kk0 + g * 8;
            const size_t gb = (size_t)(n0 + row) * ldk + kk0 + g * 8;
            *(short8v*)&As_hi[ldsoff] = *(const short8v*)(Ahi + ga);
            *(short8v*)&As_lo[ldsoff] = *(const short8v*)(Alo + ga);
            *(short8v*)&Bs_hi[ldsoff] = *(const short8v*)(Bhi + gb);
            *(short8v*)&Bs_lo[ldsoff] = *(const short8v*)(Blo + gb);
        }
        __syncthreads();

        #pragma unroll
        for (int ks = 0; ks < 2; ++ks) {
            short8v ah[4], al[4], bh[4], bl[4];
            const int g = ks * 4 + g4;        // k-granule 0..7
            #pragma unroll
            for (int f = 0; f < 4; ++f) {
                int arow = wr + f * 16 + r15;
                int aoff = arow * 64 + ((g ^ (arow & 7)) << 3);
                ah[f] = *(const short8v*)&As_hi[aoff];
                al[f] = *(const short8v*)&As_lo[aoff];
                int brow = wc + f * 16 + r15;
                int boff = brow * 64 + ((g ^ (brow & 7)) << 3);
                bh[f] = *(const short8v*)&Bs_hi[boff];
                bl[f] = *(const short8v*)&Bs_lo[boff];
            }
            #pragma unroll
            for (int mf = 0; mf < 4; ++mf) {
                #pragma unroll
                for (int nf = 0; nf < 4; ++nf) {
                    acc[mf][nf] = __builtin_amdgcn_mfma_f32_16x16x32_bf16(ah[mf], bh[nf], acc[mf][nf], 0, 0, 0);
                    acc[mf][nf] = __builtin_amdgcn_mfma_f32_16x16x32_bf16(ah[mf], bl[nf], acc[mf][nf], 0, 0, 0);
                    acc[mf][nf] = __builtin_amdgcn_mfma_f32_16x16x32_bf16(al[mf], bh[nf], acc[mf][nf], 0, 0, 0);
                }
            }
        }
        __syncthreads();
    }

    // epilogue: C/D mapping col = lane&15, row = (lane>>4)*4 + reg  [m89-verified]
    float* cp = Cpart + (size_t)blockIdx.z * 256 * ldc;
    #pragma unroll
    for (int mf = 0; mf < 4; ++mf) {
        #pragma unroll
        for (int nf = 0; nf < 4; ++nf) {
            #pragma unroll
            for (int r = 0; r < 4; ++r) {
                int m = m0 + wr + mf * 16 + g4 * 4 + r;
                int n = n0 + wc + nf * 16 + r15;
                cp[(size_t)m * ldc + n] = acc[mf][nf][r];
            }
        }
    }
}

// ------------- reduce GEMM1 partials + bias -> agg as bf16 hi/lo --------------
__global__ __launch_bounds__(256) void reduce_agg_kernel(const float* __restrict__ Cpart,
                                                         const float* __restrict__ conv_b,
                                                         unsigned short* __restrict__ agg_hi,
                                                         unsigned short* __restrict__ agg_lo) {
    int idx = blockIdx.x * 256 + threadIdx.x;   // < 256*1024
    int n = idx & (N1P - 1);
    float s = 0.f;
    if (n < P_N) {
        s = conv_b[n];
        #pragma unroll
        for (int z = 0; z < SK; ++z) s += Cpart[(size_t)z * (B_N * N1P) + idx];
    }
    unsigned short h, l;
    split_hilo(s, h, l);
    agg_hi[idx] = h; agg_lo[idx] = l;
}

// ------------- reduce GEMM2 partials + bias -> final f32 output ---------------
__global__ __launch_bounds__(256) void reduce_out_kernel(const float* __restrict__ Cpart,
                                                         const float* __restrict__ out_b,
                                                         float* __restrict__ out) {
    int idx = blockIdx.x * 256 + threadIdx.x;   // < 256*512
    int n = idx & (OUT_N - 1);
    float s = out_b[n];
    #pragma unroll
    for (int z = 0; z < SK; ++z) s += Cpart[(size_t)z * (B_N * OUT_N) + idx];
    out[idx] = s;
}

extern "C" void kernel_launch(void* const* d_in, const int* in_sizes, int n_in,
                              void* d_out, int out_size, void* d_ws, size_t ws_size,
                              hipStream_t stream) {
    const float* x           = (const float*)d_in[0];
    const float* noise       = (const float*)d_in[1];
    const float* fb_w        = (const float*)d_in[2];
    const float* fb_b        = (const float*)d_in[3];
    const float* decay_param = (const float*)d_in[4];
    const float* conv_w      = (const float*)d_in[5];  // [P][3P] flat NT layout
    const float* conv_b      = (const float*)d_in[6];
    const float* out_w       = (const float*)d_in[7];  // [OUT, P]
    const float* out_b       = (const float*)d_in[8];
    float* out = (float*)d_out;

    // ---- workspace carve (bytes), all offsets 16B-aligned ----
    char* ws = (char*)d_ws;
    size_t off = 0;
    float* fb = (float*)(ws + off);                 off += 1024;
    unsigned short* Thi = (unsigned short*)(ws + off); off += (size_t)B_N * K1P * 2;   // 1.57 MB
    unsigned short* Tlo = (unsigned short*)(ws + off); off += (size_t)B_N * K1P * 2;
    unsigned short* Whi = (unsigned short*)(ws + off); off += (size_t)N1P * K1P * 2;   // 6.29 MB
    unsigned short* Wlo = (unsigned short*)(ws + off); off += (size_t)N1P * K1P * 2;
    unsigned short* Ohi = (unsigned short*)(ws + off); off += (size_t)OUT_N * K2P * 2; // 1.05 MB
    unsigned short* Olo = (unsigned short*)(ws + off); off += (size_t)OUT_N * K2P * 2;
    unsigned short* Ahi2 = (unsigned short*)(ws + off); off += (size_t)B_N * K2P * 2;  // 0.52 MB
    unsigned short* Alo2 = (unsigned short*)(ws + off); off += (size_t)B_N * K2P * 2;
    float* Cpart = (float*)(ws + off);              off += (size_t)SK * B_N * N1P * 4; // 16.8 MB (shared by both GEMMs)

    // 1. feedback GEMV
    fb_kernel<<<B_N, 256, 0, stream>>>(x, fb_w, fb_b, fb);

    // 2. SDE time reduction -> T as bf16 hi/lo [256][3072] (zero-padded)
    sde_reduce_kernel<<<B_N * 4, 256, 0, stream>>>(noise, fb, decay_param, Thi, Tlo);

    // 3. weight conversions (pad + hi/lo split)
    {
        int total1 = N1P * K1P;   // 1024*3072
        cvt_pad_kernel<<<(total1 + 255) / 256, 256, 0, stream>>>(conv_w, Whi, Wlo, P_N, 3 * P_N, K1P, total1);
        int total2 = OUT_N * K2P; // 512*1024
        cvt_pad_kernel<<<(total2 + 255) / 256, 256, 0, stream>>>(out_w, Ohi, Olo, OUT_N, P_N, K2P, total2);
    }

    // 4. GEMM1: Cpart = T[256,3072] * W[1024,3072]^T (hi/lo 3-term), split-K=16
    {
        dim3 grid(N1P / 128, B_N / 128, SK);      // 8 x 2 x 16
        gemm_hilo_mfma<<<grid, 256, 0, stream>>>(Thi, Tlo, Whi, Wlo, Cpart, K1P, K1P / SK, N1P);
        reduce_agg_kernel<<<(B_N * N1P) / 256, 256, 0, stream>>>(Cpart, conv_b, Ahi2, Alo2);
    }

    // 5. GEMM2: Cpart = agg[256,1024] * out_w[512,1024]^T (hi/lo 3-term), split-K=16
    {
        dim3 grid(OUT_N / 128, B_N / 128, SK);    // 4 x 2 x 16
        gemm_hilo_mfma<<<grid, 256, 0, stream>>>(Ahi2, Alo2, Ohi, Olo, Cpart, K2P, K2P / SK, OUT_N);
        reduce_out_kernel<<<(B_N * OUT_N) / 256, 256, 0, stream>>>(Cpart, out_b, out);
    }
}

// Round 3
// 57.574 us; speedup vs baseline: 2.1330x; 1.2367x over previous
//
#include <hip/hip_runtime.h>
#include <hip/hip_bf16.h>

#define B_N   256
#define IN_N  1024
#define OUT_N 512
#define P_N   1000
#define NS_N  128

#define K1P   3072   // padded K of GEMM1 (3*P_N -> 3072)
#define N1P   1024   // padded N of GEMM1
#define K2P   1024   // padded K of GEMM2
#define SK    16     // split-K factor

typedef __attribute__((ext_vector_type(8))) short short8v;
typedef __attribute__((ext_vector_type(4))) float f32x4;

__device__ __forceinline__ float sigmoid_f(float z) { return 1.0f / (1.0f + __expf(-z)); }

// exact two-term split: x ~= hi + lo (lo captures residual exactly up to bf16 rounding of lo)
__device__ __forceinline__ void split8(float4 v0, float4 v1, short8v& h, short8v& l) {
    float vv[8] = {v0.x, v0.y, v0.z, v0.w, v1.x, v1.y, v1.z, v1.w};
    #pragma unroll
    for (int j = 0; j < 8; ++j) {
        __hip_bfloat16 hb = __float2bfloat16(vv[j]);
        float r = vv[j] - __bfloat162float(hb);
        __hip_bfloat16 lb = __float2bfloat16(r);
        h[j] = (short)__bfloat16_as_ushort(hb);
        l[j] = (short)__bfloat16_as_ushort(lb);
    }
}

// ---- fused feedback + SDE time-reduction -> T f32 [B_N][K1P] (zero-padded) ----
// paths[t] = fb*sd * sum_{s<=t} retain^{t-s} eps[s]
// L = sum_s retain^{127-s} eps[s]; A = (sumE - retain*L)/(1-retain); F = eps[0]
// T[b, 3i+k]: k=0 -> scale*(A-L), k=1 -> scale*A, k=2 -> scale*(A-F)
__global__ __launch_bounds__(256) void sde_fused_kernel(const float* __restrict__ x,
                                                        const float* __restrict__ fb_w,
                                                        const float* __restrict__ fb_b,
                                                        const float* __restrict__ noise,
                                                        const float* __restrict__ decay_param,
                                                        float* __restrict__ T) {
    int b = blockIdx.x;
    int t = threadIdx.x;

    // feedback dot-product for this batch row
    float4 xv = ((const float4*)(x + (size_t)b * IN_N))[t];
    float4 wv = ((const float4*)fb_w)[t];
    float s = xv.x * wv.x + xv.y * wv.y + xv.z * wv.z + xv.w * wv.w;
    __shared__ float red[256];
    red[t] = s;
    __syncthreads();
    for (int off = 128; off >= 1; off >>= 1) {
        if (t < off) red[t] += red[t + off];
        __syncthreads();
    }
    float fbv = sigmoid_f(red[0] + fb_b[0]);

    // SDE column reduction, 4 columns per thread (float4 rows)
    float decay = sigmoid_f(decay_param[0]) * 0.5f;
    const float dt = 1.0f / NS_N;
    float retain = 1.0f - decay * dt;
    float inv_omr = 1.0f / (decay * dt);

    int c0 = t * 4;
    bool act = (c0 < P_N);              // threads 250..255 produce zero padding
    const float* base = noise + (size_t)b * NS_N * P_N + (act ? c0 : 0);

    float4 sumE = {0, 0, 0, 0}, L = {0, 0, 0, 0}, F = {0, 0, 0, 0};
    float rp = 1.0f;                     // retain^{127-s}, s descending
    #pragma unroll 8
    for (int s_ = NS_N - 1; s_ >= 0; --s_) {
        float4 e = *(const float4*)(base + (size_t)s_ * P_N);
        sumE.x += e.x; sumE.y += e.y; sumE.z += e.z; sumE.w += e.w;
        L.x += rp * e.x; L.y += rp * e.y; L.z += rp * e.z; L.w += rp * e.w;
        if (s_ == 0) F = e;
        rp *= retain;
    }

    float sd = sqrtf(dt);
    float scale = act ? (fbv * sd * (1.0f / NS_N)) : 0.0f;
    float* tp = T + (size_t)b * K1P + 3 * (size_t)c0;   // 12*t, covers cols 0..3071
    float Ls[4] = {L.x, L.y, L.z, L.w};
    float Ss[4] = {sumE.x, sumE.y, sumE.z, sumE.w};
    float Fs[4] = {F.x, F.y, F.z, F.w};
    #pragma unroll
    for (int j = 0; j < 4; ++j) {
        float Aj = (Ss[j] - retain * Ls[j]) * inv_omr;
        tp[3 * j + 0] = scale * (Aj - Ls[j]);
        tp[3 * j + 1] = scale * Aj;
        tp[3 * j + 2] = scale * (Aj - Fs[j]);
    }
}

// ---- f32-in MFMA NT GEMM with on-the-fly bf16 hi/lo split, split-K partials ----
// C = A[M,K]*B[N,K]^T with 3-term hi/lo MFMA (drop lo*lo). BM=BN=128, BK=64.
// A assumed dense/padded-valid; B guarded by (Nvalid, Kvalid), OOB -> 0.
// LDS XOR-swizzled at 16B granules: slot(row,g) holds granule g^(row&7).
__global__ __launch_bounds__(256) void gemm_f32_mfma(const float* __restrict__ A,
                                                     const float* __restrict__ B,
                                                     float* __restrict__ Cpart,
                                                     int lda, int ldb,
                                                     int Nvalid, int Kvalid,
                                                     int Kper, int ldc) {
    __shared__ __align__(16) unsigned short As_hi[128 * 64];
    __shared__ __align__(16) unsigned short As_lo[128 * 64];
    __shared__ __align__(16) unsigned short Bs_hi[128 * 64];
    __shared__ __align__(16) unsigned short Bs_lo[128 * 64];

    const int tid  = threadIdx.x;
    const int lane = tid & 63;
    const int wave = tid >> 6;
    const int r15  = lane & 15;
    const int g4   = lane >> 4;
    const int n0 = blockIdx.x * 128;
    const int m0 = blockIdx.y * 128;
    const size_t kbeg = (size_t)blockIdx.z * Kper;

    f32x4 acc[4][4] = {};
    const int wr = (wave >> 1) * 64;
    const int wc = (wave & 1) * 64;

    for (int kt = 0; kt < Kper; kt += 64) {
        const size_t kk0 = kbeg + kt;
        #pragma unroll
        for (int c = 0; c < 4; ++c) {
            int chunk = tid + c * 256;        // 0..1023
            int row = chunk >> 3;             // 0..127
            int g   = chunk & 7;              // 16B-out granule (8 elems)
            int ldsoff = row * 64 + ((g ^ (row & 7)) << 3);

            const float* ap = A + (size_t)(m0 + row) * lda + kk0 + g * 8;
            float4 a0 = *(const float4*)ap;
            float4 a1 = *(const float4*)(ap + 4);

            float4 b0 = {0, 0, 0, 0}, b1 = {0, 0, 0, 0};
            if ((n0 + row) < Nvalid && (int)(kk0 + g * 8) < Kvalid) {
                const float* bp = B + (size_t)(n0 + row) * ldb + kk0 + g * 8;
                b0 = *(const float4*)bp;
                b1 = *(const float4*)(bp + 4);
            }

            short8v ah, al, bh, bl;
            split8(a0, a1, ah, al);
            split8(b0, b1, bh, bl);
            *(short8v*)&As_hi[ldsoff] = ah;
            *(short8v*)&As_lo[ldsoff] = al;
            *(short8v*)&Bs_hi[ldsoff] = bh;
            *(short8v*)&Bs_lo[ldsoff] = bl;
        }
        __syncthreads();

        #pragma unroll
        for (int ks = 0; ks < 2; ++ks) {
            short8v ah[4], al[4], bh[4], bl[4];
            const int g = ks * 4 + g4;        // k-granule 0..7
            #pragma unroll
            for (int f = 0; f < 4; ++f) {
                int arow = wr + f * 16 + r15;
                int aoff = arow * 64 + ((g ^ (arow & 7)) << 3);
                ah[f] = *(const short8v*)&As_hi[aoff];
                al[f] = *(const short8v*)&As_lo[aoff];
                int brow = wc + f * 16 + r15;
                int boff = brow * 64 + ((g ^ (brow & 7)) << 3);
                bh[f] = *(const short8v*)&Bs_hi[boff];
                bl[f] = *(const short8v*)&Bs_lo[boff];
            }
            #pragma unroll
            for (int mf = 0; mf < 4; ++mf) {
                #pragma unroll
                for (int nf = 0; nf < 4; ++nf) {
                    acc[mf][nf] = __builtin_amdgcn_mfma_f32_16x16x32_bf16(ah[mf], bh[nf], acc[mf][nf], 0, 0, 0);
                    acc[mf][nf] = __builtin_amdgcn_mfma_f32_16x16x32_bf16(ah[mf], bl[nf], acc[mf][nf], 0, 0, 0);
                    acc[mf][nf] = __builtin_amdgcn_mfma_f32_16x16x32_bf16(al[mf], bh[nf], acc[mf][nf], 0, 0, 0);
                }
            }
        }
        __syncthreads();
    }

    // C/D mapping: col = lane&15, row = (lane>>4)*4 + reg  [m89-verified]
    float* cp = Cpart + (size_t)blockIdx.z * 256 * ldc;
    #pragma unroll
    for (int mf = 0; mf < 4; ++mf) {
        #pragma unroll
        for (int nf = 0; nf < 4; ++nf) {
            #pragma unroll
            for (int r = 0; r < 4; ++r) {
                int m = m0 + wr + mf * 16 + g4 * 4 + r;
                int n = n0 + wc + nf * 16 + r15;
                cp[(size_t)m * ldc + n] = acc[mf][nf][r];
            }
        }
    }
}

// ---- reduce GEMM1 partials + bias -> agg f32 [B_N][K2P] (zero-padded) ----
__global__ __launch_bounds__(256) void reduce_agg_kernel(const float* __restrict__ Cpart,
                                                         const float* __restrict__ conv_b,
                                                         float* __restrict__ agg) {
    int idx = blockIdx.x * 256 + threadIdx.x;   // < 256*1024
    int n = idx & (N1P - 1);
    float s = 0.f;
    if (n < P_N) {
        s = conv_b[n];
        #pragma unroll
        for (int z = 0; z < SK; ++z) s += Cpart[(size_t)z * (B_N * N1P) + idx];
    }
    agg[idx] = s;
}

// ---- reduce GEMM2 partials + bias -> final f32 output ----
__global__ __launch_bounds__(256) void reduce_out_kernel(const float* __restrict__ Cpart,
                                                         const float* __restrict__ out_b,
                                                         float* __restrict__ out) {
    int idx = blockIdx.x * 256 + threadIdx.x;   // < 256*512
    int n = idx & (OUT_N - 1);
    float s = out_b[n];
    #pragma unroll
    for (int z = 0; z < SK; ++z) s += Cpart[(size_t)z * (B_N * OUT_N) + idx];
    out[idx] = s;
}

extern "C" void kernel_launch(void* const* d_in, const int* in_sizes, int n_in,
                              void* d_out, int out_size, void* d_ws, size_t ws_size,
                              hipStream_t stream) {
    const float* x           = (const float*)d_in[0];
    const float* noise       = (const float*)d_in[1];
    const float* fb_w        = (const float*)d_in[2];
    const float* fb_b        = (const float*)d_in[3];
    const float* decay_param = (const float*)d_in[4];
    const float* conv_w      = (const float*)d_in[5];  // [P][3P] flat NT layout
    const float* conv_b      = (const float*)d_in[6];
    const float* out_w       = (const float*)d_in[7];  // [OUT, P]
    const float* out_b       = (const float*)d_in[8];
    float* out = (float*)d_out;

    // workspace carve (16B-aligned)
    char* ws = (char*)d_ws;
    size_t off = 0;
    float* T     = (float*)(ws + off); off += (size_t)B_N * K1P * 4;        // 3.1 MB
    float* agg   = (float*)(ws + off); off += (size_t)B_N * K2P * 4;        // 1.0 MB
    float* Cpart = (float*)(ws + off); off += (size_t)SK * B_N * N1P * 4;   // 16.8 MB

    // 1. fused feedback + SDE reduction -> T [256][3072]
    sde_fused_kernel<<<B_N, 256, 0, stream>>>(x, fb_w, fb_b, noise, decay_param, T);

    // 2. GEMM1: Cpart = T[256,3072] * conv_w[1000,3000]^T (pad-guarded), split-K=16
    {
        dim3 grid(N1P / 128, B_N / 128, SK);      // 8 x 2 x 16
        gemm_f32_mfma<<<grid, 256, 0, stream>>>(T, conv_w, Cpart,
                                                K1P, 3 * P_N, P_N, 3 * P_N,
                                                K1P / SK, N1P);
        reduce_agg_kernel<<<(B_N * N1P) / 256, 256, 0, stream>>>(Cpart, conv_b, agg);
    }

    // 3. GEMM2: Cpart = agg[256,1024] * out_w[512,1000]^T (pad-guarded), split-K=16
    {
        dim3 grid(OUT_N / 128, B_N / 128, SK);    // 4 x 2 x 16
        gemm_f32_mfma<<<grid, 256, 0, stream>>>(agg, out_w, Cpart,
                                                K2P, P_N, OUT_N, P_N,
                                                K2P / SK, OUT_N);
        reduce_out_kernel<<<(B_N * OUT_N) / 256, 256, 0, stream>>>(Cpart, out_b, out);
    }
}

// Round 4
// 53.404 us; speedup vs baseline: 2.2995x; 1.0781x over previous
//
#include <hip/hip_runtime.h>
#include <hip/hip_bf16.h>

#define B_N   256
#define IN_N  1024
#define OUT_N 512
#define P_N   1000
#define NS_N  128

#define K1P   3072   // padded K of GEMM1 (3*P_N)
#define N1P   1024   // padded N of GEMM1
#define K2P   1024   // padded K of GEMM2
#define SK    16     // split-K factor

typedef __attribute__((ext_vector_type(8))) short short8v;
typedef __attribute__((ext_vector_type(4))) float f32x4;
typedef unsigned short ushort_t;

__device__ __forceinline__ float sigmoid_f(float z) { return 1.0f / (1.0f + __expf(-z)); }

__device__ __forceinline__ void split1(float x, ushort_t& h, ushort_t& l) {
    __hip_bfloat16 hb = __float2bfloat16(x);
    float r = x - __bfloat162float(hb);
    __hip_bfloat16 lb = __float2bfloat16(r);
    h = __bfloat16_as_ushort(hb);
    l = __bfloat16_as_ushort(lb);
}

__device__ __forceinline__ void split8(float4 v0, float4 v1, short8v& h, short8v& l) {
    float vv[8] = {v0.x, v0.y, v0.z, v0.w, v1.x, v1.y, v1.z, v1.w};
    #pragma unroll
    for (int j = 0; j < 8; ++j) {
        ushort_t hh, ll;
        split1(vv[j], hh, ll);
        h[j] = (short)hh;
        l[j] = (short)ll;
    }
}

// ---- fused feedback + SDE time-reduction -> T as bf16 hi/lo [B_N][K1P] ----
// paths[t] = fb*sd * sum_{s<=t} retain^{t-s} eps[s]
// L = sum_s retain^{127-s} eps[s]; A = (sumE - retain*L)/(1-retain); F = eps[0]
// T[b, 3i+k]: k=0 -> scale*(A-L), k=1 -> scale*A, k=2 -> scale*(A-F)
__global__ __launch_bounds__(256) void sde_fused_kernel(const float* __restrict__ x,
                                                        const float* __restrict__ fb_w,
                                                        const float* __restrict__ fb_b,
                                                        const float* __restrict__ noise,
                                                        const float* __restrict__ decay_param,
                                                        ushort_t* __restrict__ Thi,
                                                        ushort_t* __restrict__ Tlo) {
    int b = blockIdx.x;
    int chunk = blockIdx.y;           // 0 or 1: column halves
    int t = threadIdx.x;

    // feedback dot-product for this batch row (redundant per chunk, cheap)
    float4 xv = ((const float4*)(x + (size_t)b * IN_N))[t];
    float4 wv = ((const float4*)fb_w)[t];
    float s = xv.x * wv.x + xv.y * wv.y + xv.z * wv.z + xv.w * wv.w;
    __shared__ float red[256];
    red[t] = s;
    __syncthreads();
    for (int off = 128; off >= 1; off >>= 1) {
        if (t < off) red[t] += red[t + off];
        __syncthreads();
    }
    float fbv = sigmoid_f(red[0] + fb_b[0]);

    float decay = sigmoid_f(decay_param[0]) * 0.5f;
    const float dt = 1.0f / NS_N;
    float retain = 1.0f - decay * dt;
    float inv_omr = 1.0f / (decay * dt);

    int c0 = chunk * 512 + t * 2;     // 2 columns per thread (float2)
    bool act = (c0 < P_N);
    const float* base = noise + (size_t)b * NS_N * P_N + (act ? c0 : 0);

    float sE0 = 0.f, sE1 = 0.f, L0 = 0.f, L1 = 0.f, F0 = 0.f, F1 = 0.f;
    float rp = 1.0f;                  // retain^{127-s}, s descending
    #pragma unroll 8
    for (int s_ = NS_N - 1; s_ >= 0; --s_) {
        float2 e = *(const float2*)(base + (size_t)s_ * P_N);
        sE0 += e.x; sE1 += e.y;
        L0 += rp * e.x; L1 += rp * e.y;
        if (s_ == 0) { F0 = e.x; F1 = e.y; }
        rp *= retain;
    }

    float sd = sqrtf(dt);
    float scale = act ? (fbv * sd * (1.0f / NS_N)) : 0.0f;
    size_t tb = (size_t)b * K1P + 3 * (size_t)c0;
    float Ls[2] = {L0, L1}, Ss[2] = {sE0, sE1}, Fs[2] = {F0, F1};
    #pragma unroll
    for (int j = 0; j < 2; ++j) {
        float Aj = (Ss[j] - retain * Ls[j]) * inv_omr;
        float t0 = scale * (Aj - Ls[j]);
        float t1 = scale * Aj;
        float t2 = scale * (Aj - Fs[j]);
        ushort_t h, l;
        split1(t0, h, l); Thi[tb + 3 * j + 0] = h; Tlo[tb + 3 * j + 0] = l;
        split1(t1, h, l); Thi[tb + 3 * j + 1] = h; Tlo[tb + 3 * j + 1] = l;
        split1(t2, h, l); Thi[tb + 3 * j + 2] = h; Tlo[tb + 3 * j + 2] = l;
    }
}

// ---- MFMA NT GEMM: A pre-split bf16 hi/lo, B f32 split on the fly ----
// C = (Ahi+Alo)[M,K] * B[N,K]^T (3-term, drop lo*lo). BM=BN=128, BK=64.
// 512 threads = 8 waves in 2(row)x4(col); wave tile 64x32 = 4x2 frags of 16x16.
// LDS XOR-swizzled at 16B granules: slot(row,g) holds granule g^(row&7).
__global__ __launch_bounds__(512) void gemm_hilo_mfma(const ushort_t* __restrict__ Ahi,
                                                      const ushort_t* __restrict__ Alo,
                                                      const float* __restrict__ B,
                                                      float* __restrict__ Cpart,
                                                      int lda, int ldb,
                                                      int Nvalid, int Kvalid,
                                                      int Kper, int ldc) {
    __shared__ __align__(16) ushort_t As_hi[128 * 64];
    __shared__ __align__(16) ushort_t As_lo[128 * 64];
    __shared__ __align__(16) ushort_t Bs_hi[128 * 64];
    __shared__ __align__(16) ushort_t Bs_lo[128 * 64];

    const int tid  = threadIdx.x;
    const int lane = tid & 63;
    const int wave = tid >> 6;
    const int r15  = lane & 15;
    const int g4   = lane >> 4;
    const int wrow = wave >> 2;       // 0..1
    const int wcol = wave & 3;        // 0..3
    const int n0 = blockIdx.x * 128;
    const int m0 = blockIdx.y * 128;
    const size_t kbeg = (size_t)blockIdx.z * Kper;

    f32x4 acc[4][2] = {};

    for (int kt = 0; kt < Kper; kt += 64) {
        const size_t kk0 = kbeg + kt;
        #pragma unroll
        for (int c = 0; c < 2; ++c) {
            int chunk = tid + c * 512;        // 0..1023
            int row = chunk >> 3;             // 0..127
            int g   = chunk & 7;              // 16B granule (8 elems)
            int ldsoff = row * 64 + ((g ^ (row & 7)) << 3);

            const size_t ka = (size_t)(m0 + row) * lda + kk0 + g * 8;
            *(short8v*)&As_hi[ldsoff] = *(const short8v*)(Ahi + ka);
            *(short8v*)&As_lo[ldsoff] = *(const short8v*)(Alo + ka);

            float4 b0 = {0, 0, 0, 0}, b1 = {0, 0, 0, 0};
            if ((n0 + row) < Nvalid && (int)(kk0 + g * 8) < Kvalid) {
                const float* bp = B + (size_t)(n0 + row) * ldb + kk0 + g * 8;
                b0 = *(const float4*)bp;
                b1 = *(const float4*)(bp + 4);
            }
            short8v bh, bl;
            split8(b0, b1, bh, bl);
            *(short8v*)&Bs_hi[ldsoff] = bh;
            *(short8v*)&Bs_lo[ldsoff] = bl;
        }
        __syncthreads();

        #pragma unroll
        for (int ks = 0; ks < 2; ++ks) {
            const int g = ks * 4 + g4;        // k-granule 0..7
            short8v ah[4], al[4], bh[2], bl[2];
            #pragma unroll
            for (int f = 0; f < 4; ++f) {
                int arow = wrow * 64 + f * 16 + r15;
                int aoff = arow * 64 + ((g ^ (arow & 7)) << 3);
                ah[f] = *(const short8v*)&As_hi[aoff];
                al[f] = *(const short8v*)&As_lo[aoff];
            }
            #pragma unroll
            for (int f = 0; f < 2; ++f) {
                int brow = wcol * 32 + f * 16 + r15;
                int boff = brow * 64 + ((g ^ (brow & 7)) << 3);
                bh[f] = *(const short8v*)&Bs_hi[boff];
                bl[f] = *(const short8v*)&Bs_lo[boff];
            }
            #pragma unroll
            for (int mf = 0; mf < 4; ++mf) {
                #pragma unroll
                for (int nf = 0; nf < 2; ++nf) {
                    acc[mf][nf] = __builtin_amdgcn_mfma_f32_16x16x32_bf16(ah[mf], bh[nf], acc[mf][nf], 0, 0, 0);
                    acc[mf][nf] = __builtin_amdgcn_mfma_f32_16x16x32_bf16(ah[mf], bl[nf], acc[mf][nf], 0, 0, 0);
                    acc[mf][nf] = __builtin_amdgcn_mfma_f32_16x16x32_bf16(al[mf], bh[nf], acc[mf][nf], 0, 0, 0);
                }
            }
        }
        __syncthreads();
    }

    // C/D mapping: col = lane&15, row = (lane>>4)*4 + reg  [m89-verified]
    float* cp = Cpart + (size_t)blockIdx.z * 256 * ldc;
    #pragma unroll
    for (int mf = 0; mf < 4; ++mf) {
        #pragma unroll
        for (int nf = 0; nf < 2; ++nf) {
            #pragma unroll
            for (int r = 0; r < 4; ++r) {
                int m = m0 + wrow * 64 + mf * 16 + g4 * 4 + r;
                int n = n0 + wcol * 32 + nf * 16 + r15;
                cp[(size_t)m * ldc + n] = acc[mf][nf][r];
            }
        }
    }
}

// ---- reduce GEMM1 partials + bias -> agg as bf16 hi/lo [B_N][K2P] ----
__global__ __launch_bounds__(256) void reduce_agg_kernel(const float* __restrict__ Cpart,
                                                         const float* __restrict__ conv_b,
                                                         ushort_t* __restrict__ agg_hi,
                                                         ushort_t* __restrict__ agg_lo) {
    int idx = blockIdx.x * 256 + threadIdx.x;   // < 256*1024
    int n = idx & (N1P - 1);
    float s = 0.f;
    if (n < P_N) {
        s = conv_b[n];
        #pragma unroll
        for (int z = 0; z < SK; ++z) s += Cpart[(size_t)z * (B_N * N1P) + idx];
    }
    ushort_t h, l;
    split1(s, h, l);
    agg_hi[idx] = h;
    agg_lo[idx] = l;
}

// ---- reduce GEMM2 partials + bias -> final f32 output ----
__global__ __launch_bounds__(256) void reduce_out_kernel(const float* __restrict__ Cpart,
                                                         const float* __restrict__ out_b,
                                                         float* __restrict__ out) {
    int idx = blockIdx.x * 256 + threadIdx.x;   // < 256*512
    int n = idx & (OUT_N - 1);
    float s = out_b[n];
    #pragma unroll
    for (int z = 0; z < SK; ++z) s += Cpart[(size_t)z * (B_N * OUT_N) + idx];
    out[idx] = s;
}

extern "C" void kernel_launch(void* const* d_in, const int* in_sizes, int n_in,
                              void* d_out, int out_size, void* d_ws, size_t ws_size,
                              hipStream_t stream) {
    const float* x           = (const float*)d_in[0];
    const float* noise       = (const float*)d_in[1];
    const float* fb_w        = (const float*)d_in[2];
    const float* fb_b        = (const float*)d_in[3];
    const float* decay_param = (const float*)d_in[4];
    const float* conv_w      = (const float*)d_in[5];  // [P][3P] flat NT layout
    const float* conv_b      = (const float*)d_in[6];
    const float* out_w       = (const float*)d_in[7];  // [OUT, P]
    const float* out_b       = (const float*)d_in[8];
    float* out = (float*)d_out;

    // workspace carve (16B-aligned)
    char* ws = (char*)d_ws;
    size_t off = 0;
    ushort_t* Thi   = (ushort_t*)(ws + off); off += (size_t)B_N * K1P * 2;      // 1.57 MB
    ushort_t* Tlo   = (ushort_t*)(ws + off); off += (size_t)B_N * K1P * 2;
    ushort_t* AgHi  = (ushort_t*)(ws + off); off += (size_t)B_N * K2P * 2;      // 0.52 MB
    ushort_t* AgLo  = (ushort_t*)(ws + off); off += (size_t)B_N * K2P * 2;
    float*    Cpart = (float*)(ws + off);    off += (size_t)SK * B_N * N1P * 4; // 16.8 MB

    // 1. fused feedback + SDE reduction -> T hi/lo [256][3072]
    {
        dim3 grid(B_N, 2);
        sde_fused_kernel<<<grid, 256, 0, stream>>>(x, fb_w, fb_b, noise, decay_param, Thi, Tlo);
    }

    // 2. GEMM1: Cpart = T[256,3072] * conv_w[1000,3000]^T, split-K=16
    {
        dim3 grid(N1P / 128, B_N / 128, SK);      // 8 x 2 x 16
        gemm_hilo_mfma<<<grid, 512, 0, stream>>>(Thi, Tlo, conv_w, Cpart,
                                                 K1P, 3 * P_N, P_N, 3 * P_N,
                                                 K1P / SK, N1P);
        reduce_agg_kernel<<<(B_N * N1P) / 256, 256, 0, stream>>>(Cpart, conv_b, AgHi, AgLo);
    }

    // 3. GEMM2: Cpart = agg[256,1024] * out_w[512,1000]^T, split-K=16
    {
        dim3 grid(OUT_N / 128, B_N / 128, SK);    // 4 x 2 x 16
        gemm_hilo_mfma<<<grid, 512, 0, stream>>>(AgHi, AgLo, out_w, Cpart,
                                                 K2P, P_N, OUT_N, P_N,
                                                 K2P / SK, OUT_N);
        reduce_out_kernel<<<(B_N * OUT_N) / 256, 256, 0, stream>>>(Cpart, out_b, out);
    }
}